// Round 5
// baseline (129.494 us; speedup 1.0000x reference)
//
#include <hip/hip_runtime.h>
#include <math.h>

// Problem constants
constexpr int NT = 32;     // components
constexpr int ND = 1024;   // dim
constexpr int NB = 4096;   // batch
constexpr int NBLK = 512;  // main-kernel grid size (must stay co-resident)

// Workspace layout (float offsets)
//  ivc : [256][32][4] chunk-major inv_var            @ 0       (32768 floats)
//  m2c : [256][32][4] chunk-major (-2*mu*inv_var)    @ 32768   (32768)
//  c2  : [32]  sum(mu^2*inv_var)                     @ 65536
//  Ng  : [32]  sum_b kl_gaussian                     @ 65568
//  Npi : [32]  sum_b log_pi                          @ 65600
//  cnt : [1]   grid-barrier arrival counter (uint)   @ 65632
constexpr int OFF_M2C = 32768;
constexpr int OFF_C2  = 65536;
constexpr int OFF_NG  = 65568;
constexpr int OFF_NPI = 65600;
constexpr int OFF_CNT = 65632;

// ---------------------------------------------------------------------------
// Kernel A: per-component stats + zeroing of accumulators/barrier counter.
// grid = 32 (one block per component t), block = 256 (one chunk of 4 d's each)
// ---------------------------------------------------------------------------
__global__ __launch_bounds__(256) void k_stats(const float* __restrict__ mu,
                                               const float* __restrict__ rho,
                                               float* __restrict__ ws,
                                               float* __restrict__ out) {
  float* ivc = ws;
  float* m2c = ws + OFF_M2C;
  float* c2  = ws + OFF_C2;
  float* Ng  = ws + OFF_NG;
  float* Npi = ws + OFF_NPI;
  unsigned* cnt = reinterpret_cast<unsigned*>(ws + OFF_CNT);

  const int t = blockIdx.x;
  const int c = threadIdx.x;  // chunk index 0..255 (covers d = 4c..4c+3)

  float4 mu4  = reinterpret_cast<const float4*>(mu  + t * ND)[c];
  float4 rho4 = reinterpret_cast<const float4*>(rho + t * ND)[c];

  float rr[4] = {rho4.x, rho4.y, rho4.z, rho4.w};
  float mm[4] = {mu4.x,  mu4.y,  mu4.z,  mu4.w};
  float iv[4], m2[4];
  float c2p = 0.0f;
#pragma unroll
  for (int j = 0; j < 4; ++j) {
    float sd  = log1pf(expf(rr[j]));   // softplus
    float ivv = 1.0f / (sd * sd);
    iv[j] = ivv;
    m2[j] = -2.0f * mm[j] * ivv;
    c2p  += mm[j] * mm[j] * ivv;
  }
  float4 iv4 = {iv[0], iv[1], iv[2], iv[3]};
  float4 m24 = {m2[0], m2[1], m2[2], m2[3]};
  reinterpret_cast<float4*>(ivc)[c * NT + t] = iv4;   // chunk-major
  reinterpret_cast<float4*>(m2c)[c * NT + t] = m24;

  // block reduction of c2p (4 waves)
#pragma unroll
  for (int m = 32; m >= 1; m >>= 1) c2p += __shfl_xor(c2p, m, 64);
  __shared__ float red[4];
  const int wave = threadIdx.x >> 6, lane = threadIdx.x & 63;
  if (lane == 0) red[wave] = c2p;
  __syncthreads();
  if (threadIdx.x == 0) {
    c2[t]  = red[0] + red[1] + red[2] + red[3];
    Ng[t]  = 0.0f;
    Npi[t] = 0.0f;
    if (t == 0) {
      cnt[0] = 0u;      // re-arm grid barrier every launch (graph replays)
      out[0] = 0.0f;    // re-zero output every launch
    }
  }
}

// ---------------------------------------------------------------------------
// Kernel B+C fused: quad GEMM + kl_gaussian + log_pi + batch sums, then a
// hand-rolled grid barrier (all 512 blocks are co-resident: 512 thr, 8 KB
// LDS, __launch_bounds__(512,4) -> 2 blocks/CU x 256 CU), then mix + softmax
// + weighted mean straight from LDS. Only 256 B (Ng/Npi) crosses blocks
// after the barrier, read with agent-scope acquire loads.
// ---------------------------------------------------------------------------
__global__ __launch_bounds__(512, 4) void k_mainf(const float* __restrict__ x,
                                                  const float* __restrict__ beta,
                                                  float* __restrict__ ws,
                                                  float* __restrict__ out) {
  const float* ivc = ws;
  const float* m2c = ws + OFF_M2C;
  const float* c2  = ws + OFF_C2;
  float* Ng  = ws + OFF_NG;
  float* Npi = ws + OFF_NPI;
  unsigned* cnt = reinterpret_cast<unsigned*>(ws + OFF_CNT);

  const int tid  = threadIdx.x;
  const int q    = tid >> 6;        // wave = d-eighth (0..7)
  const int lane = tid & 63;
  const int h = lane >> 5, t = lane & 31;
  const int row0 = blockIdx.x * 8;

  __shared__ float part[8][8][32];  // [eighth][row][t] = 8 KB
  __shared__ float klds[8][32];     // kl_gaussian, persists to phase C
  __shared__ float lplds[8][32];    // log_pi,      persists to phase C
  __shared__ float red[4];

  // ---- Phase B: quad GEMM (8 rows/block, wave owns a d-eighth) ----
  // chunk c = q*32 + h*16 + i (i=0..15); float4 idx = c*32 + t (chunk-major)
  const int c0 = q * 32 + h * 16;
  const float4* ivp = reinterpret_cast<const float4*>(ivc) + (size_t)c0 * NT + t;
  const float4* m2p = reinterpret_cast<const float4*>(m2c) + (size_t)c0 * NT + t;
  // x row r at float4 idx (row0+r)*256 + c0 + i ; broadcast within each half
  const float4* xb = reinterpret_cast<const float4*>(x) + (size_t)row0 * 256 + c0;

  float a[8] = {0.f, 0.f, 0.f, 0.f, 0.f, 0.f, 0.f, 0.f};
#pragma unroll 2
  for (int i = 0; i < 16; ++i) {
    float4 iv4 = ivp[(size_t)i * NT];
    float4 m24 = m2p[(size_t)i * NT];
#pragma unroll
    for (int r = 0; r < 8; ++r) {
      float4 xv = xb[(size_t)r * 256 + i];
      // acc += x*(x*iv + m2) == x^2*iv + x*m2
      a[r] = fmaf(xv.x, fmaf(xv.x, iv4.x, m24.x), a[r]);
      a[r] = fmaf(xv.y, fmaf(xv.y, iv4.y, m24.y), a[r]);
      a[r] = fmaf(xv.z, fmaf(xv.z, iv4.z, m24.z), a[r]);
      a[r] = fmaf(xv.w, fmaf(xv.w, iv4.w, m24.w), a[r]);
    }
  }
  // combine the two 64-d sub-halves within the wave
#pragma unroll
  for (int r = 0; r < 8; ++r) a[r] += __shfl_xor(a[r], 32, 64);

  if (h == 0) {
#pragma unroll
    for (int r = 0; r < 8; ++r) part[q][r][t] = a[r];
  }
  __syncthreads();

  // epilogue on first 4 waves: rr = row-in-block (0..7), t2 = component
  const int rr = tid >> 5, t2 = tid & 31;
  if (tid < 256) {
    float quad = 0.f;
#pragma unroll
    for (int qq = 0; qq < 8; ++qq) quad += part[qq][rr][t2];
    // kl_gaussian = log_pdfs + entropy = D/2 - 0.5*quad (log_std_sum cancels)
    const float kv = 512.0f - 0.5f * (quad + c2[t2]);
    klds[rr][t2] = kv;

    // log_pi: exclusive prefix scan of log1p(-beta) within each 32-lane group
    const float b = beta[(size_t)(row0 + rr) * NT + t2];
    const float l1m = log1pf(-b);
    float s = l1m;
#pragma unroll
    for (int d = 1; d < 32; d <<= 1) {
      float v = __shfl_up(s, (unsigned)d, 32);
      if (t2 >= d) s += v;
    }
    lplds[rr][t2] = logf(b) + (s - l1m);   // exclusive prefix + log(beta)
  }
  __syncthreads();

  if (tid < 32) {
    float sg = 0.f, sp = 0.f;
#pragma unroll
    for (int r = 0; r < 8; ++r) { sg += klds[r][tid]; sp += lplds[r][tid]; }
    atomicAdd(&Ng[tid],  sg);
    atomicAdd(&Npi[tid], sp);
  }
  __syncthreads();   // drains the atomics (vmcnt) for every lane in the block

  // ---- Grid barrier: arrive + spin (all 512 blocks are co-resident) ----
  if (tid == 0) {
    __hip_atomic_fetch_add(cnt, 1u, __ATOMIC_ACQ_REL, __HIP_MEMORY_SCOPE_AGENT);
    while (__hip_atomic_load(cnt, __ATOMIC_ACQUIRE, __HIP_MEMORY_SCOPE_AGENT)
           < (unsigned)NBLK) {
      __builtin_amdgcn_s_sleep(2);
    }
  }
  __syncthreads();

  // ---- Phase C: mix + softmax over T + weighted mean (from LDS) ----
  if (tid < 256) {
    const float kg = klds[rr][t2];
    const float lp = lplds[rr][t2];
    const float ng = __hip_atomic_load(&Ng[t2],  __ATOMIC_ACQUIRE,
                                       __HIP_MEMORY_SCOPE_AGENT);
    const float np = __hip_atomic_load(&Npi[t2], __ATOMIC_ACQUIRE,
                                       __HIP_MEMORY_SCOPE_AGENT);
    const float mix  = np / (ng + np);
    const float klgm = mix * kg;
    const float kl   = klgm + (1.0f - mix) * lp;

    // softmax over the 32 t-lanes (xor masks < 32 stay within each half)
    float m = kl;
#pragma unroll
    for (int mk = 16; mk >= 1; mk >>= 1) m = fmaxf(m, __shfl_xor(m, mk, 64));
    const float e = expf(kl - m);
    float num = e * klgm, den = e;
#pragma unroll
    for (int mk = 16; mk >= 1; mk >>= 1) {
      num += __shfl_xor(num, mk, 64);
      den += __shfl_xor(den, mk, 64);
    }
    float s = num / den;           // per-row sum_t phi*klgm (replicated)
    s += __shfl_xor(s, 32, 64);    // combine the wave's two rows

    const int wv = tid >> 6, ln = tid & 63;
    if (ln == 0) red[wv] = s;
  }
  __syncthreads();
  if (tid == 0)
    atomicAdd(out, (red[0] + red[1] + red[2] + red[3]) * (1.0f / (float)NB));
}

// ---------------------------------------------------------------------------
extern "C" void kernel_launch(void* const* d_in, const int* in_sizes, int n_in,
                              void* d_out, int out_size, void* d_ws, size_t ws_size,
                              hipStream_t stream) {
  const float* x    = (const float*)d_in[0];
  const float* mu   = (const float*)d_in[1];
  const float* rho  = (const float*)d_in[2];
  const float* beta = (const float*)d_in[3];
  float* out = (float*)d_out;
  float* ws  = (float*)d_ws;

  hipLaunchKernelGGL(k_stats, dim3(32),   dim3(256), 0, stream, mu, rho, ws, out);
  hipLaunchKernelGGL(k_mainf, dim3(NBLK), dim3(512), 0, stream, x, beta, ws, out);
}

// Round 6
// 33.248 us; speedup vs baseline: 3.8948x; 3.8948x over previous
//
#include <hip/hip_runtime.h>
#include <math.h>

// Problem constants
constexpr int NT = 32;     // components
constexpr int ND = 1024;   // dim
constexpr int NB = 4096;   // batch

// Workspace layout (float offsets)
//  ivc : [256][32][4] chunk-major inv_var            @ 0       (32768 floats)
//  m2c : [256][32][4] chunk-major (-2*mu*inv_var)    @ 32768   (32768)
//  c2  : [32]  sum(mu^2*inv_var)                     @ 65536
//  Ng  : [32]  sum_b kl_gaussian                     @ 65568
//  Npi : [32]  sum_b log_pi                          @ 65600
//  klg : [B][T]                                      @ 65664   (131072)
//  lpi : [B][T]                                      @ 196736  (131072)
constexpr int OFF_M2C = 32768;
constexpr int OFF_C2  = 65536;
constexpr int OFF_NG  = 65568;
constexpr int OFF_NPI = 65600;
constexpr int OFF_KLG = 65664;
constexpr int OFF_LPI = 196736;

// ---------------------------------------------------------------------------
// Kernel A: per-component stats + zeroing of accumulators.
// grid = 32 (one block per component t), block = 256 (one chunk of 4 d's each)
// ---------------------------------------------------------------------------
__global__ __launch_bounds__(256) void k_stats(const float* __restrict__ mu,
                                               const float* __restrict__ rho,
                                               float* __restrict__ ws,
                                               float* __restrict__ out) {
  float* ivc = ws;
  float* m2c = ws + OFF_M2C;
  float* c2  = ws + OFF_C2;
  float* Ng  = ws + OFF_NG;
  float* Npi = ws + OFF_NPI;

  const int t = blockIdx.x;
  const int c = threadIdx.x;  // chunk index 0..255 (covers d = 4c..4c+3)

  float4 mu4  = reinterpret_cast<const float4*>(mu  + t * ND)[c];
  float4 rho4 = reinterpret_cast<const float4*>(rho + t * ND)[c];

  float rr[4] = {rho4.x, rho4.y, rho4.z, rho4.w};
  float mm[4] = {mu4.x,  mu4.y,  mu4.z,  mu4.w};
  float iv[4], m2[4];
  float c2p = 0.0f;
#pragma unroll
  for (int j = 0; j < 4; ++j) {
    float sd  = log1pf(expf(rr[j]));   // softplus
    float ivv = 1.0f / (sd * sd);
    iv[j] = ivv;
    m2[j] = -2.0f * mm[j] * ivv;
    c2p  += mm[j] * mm[j] * ivv;
  }
  float4 iv4 = {iv[0], iv[1], iv[2], iv[3]};
  float4 m24 = {m2[0], m2[1], m2[2], m2[3]};
  reinterpret_cast<float4*>(ivc)[c * NT + t] = iv4;   // chunk-major
  reinterpret_cast<float4*>(m2c)[c * NT + t] = m24;

  // block reduction of c2p (4 waves)
#pragma unroll
  for (int m = 32; m >= 1; m >>= 1) c2p += __shfl_xor(c2p, m, 64);
  __shared__ float red[4];
  const int wave = threadIdx.x >> 6, lane = threadIdx.x & 63;
  if (lane == 0) red[wave] = c2p;
  __syncthreads();
  if (threadIdx.x == 0) {
    c2[t]  = red[0] + red[1] + red[2] + red[3];
    Ng[t]  = 0.0f;
    Npi[t] = 0.0f;
    if (t == 0) out[0] = 0.0f;   // must re-zero every launch (graph replays)
  }
}

// ---------------------------------------------------------------------------
// Kernel B v4: LDS-staged quad GEMM + kl_gaussian + log_pi + partial sums.
// grid = 512 blocks x 512 threads (8 waves). Block owns 8 rows of x.
//
// Stage: the block's 32 KB x-slab (8 rows x 1024 f32) is loaded with 2048
// block-wide COALESCED float4 loads into LDS (streaming, latency-amortized),
// replacing the 128 per-wave 16B broadcast global loads that were
// queue/latency-bound (~35 us in rounds 1-4).
// Compute: wave q owns d-eighth (32 float4 chunks); lane (h,t): h = sub-half
// (16 chunks), t = component. x comes from LDS via broadcast ds_read_b128
// (same-address within each 32-lane half -> conflict-free, separate pipe);
// iv/m2 are the only per-iter VMEM (coalesced, 256 KB shared -> L2-hot).
// iv/m2 L2 traffic: 4096 waves x 32 KB = 128 MB (3.7 us floor); FMA floor
// 3.4 us; x stream 16.7 MB (2.7 us) -- pipes overlap.
// ---------------------------------------------------------------------------
__global__ __launch_bounds__(512, 4) void k_main(const float* __restrict__ x,
                                                 const float* __restrict__ beta,
                                                 float* __restrict__ ws) {
  const float* ivc = ws;
  const float* m2c = ws + OFF_M2C;
  const float* c2  = ws + OFF_C2;
  float* Ng  = ws + OFF_NG;
  float* Npi = ws + OFF_NPI;
  float* klg = ws + OFF_KLG;
  float* lpi = ws + OFF_LPI;

  const int tid  = threadIdx.x;
  const int q    = tid >> 6;        // wave = d-eighth (0..7)
  const int lane = tid & 63;
  const int h = lane >> 5, t = lane & 31;
  const int row0 = blockIdx.x * 8;

  __shared__ float xs[8 * 1024];    // 32 KB: block's x slab, [row][d]
  __shared__ float part[8][8][32];  // [eighth][row][t] = 8 KB

  // ---- Stage x (coalesced, block-wide) ----
  {
    const float4* xg4 = reinterpret_cast<const float4*>(x) + (size_t)row0 * 256;
    float4* xs4w = reinterpret_cast<float4*>(xs);
#pragma unroll
    for (int k = 0; k < 4; ++k) {
      xs4w[k * 512 + tid] = xg4[k * 512 + tid];
    }
  }
  __syncthreads();

  // ---- FMA loop: x from LDS (broadcast), iv/m2 from L2 ----
  // chunk c = q*32 + h*16 + i (i=0..15); float4 idx = c*32 + t (chunk-major)
  const int c0 = q * 32 + h * 16;
  const float4* ivp = reinterpret_cast<const float4*>(ivc) + (size_t)c0 * NT + t;
  const float4* m2p = reinterpret_cast<const float4*>(m2c) + (size_t)c0 * NT + t;
  const float4* xs4 = reinterpret_cast<const float4*>(xs) + c0;

  float a[8] = {0.f, 0.f, 0.f, 0.f, 0.f, 0.f, 0.f, 0.f};
#pragma unroll 4
  for (int i = 0; i < 16; ++i) {
    float4 iv4 = ivp[(size_t)i * NT];
    float4 m24 = m2p[(size_t)i * NT];
#pragma unroll
    for (int r = 0; r < 8; ++r) {
      float4 xv = xs4[r * 256 + i];   // broadcast ds_read_b128
      // acc += x*(x*iv + m2) == x^2*iv + x*m2
      a[r] = fmaf(xv.x, fmaf(xv.x, iv4.x, m24.x), a[r]);
      a[r] = fmaf(xv.y, fmaf(xv.y, iv4.y, m24.y), a[r]);
      a[r] = fmaf(xv.z, fmaf(xv.z, iv4.z, m24.z), a[r]);
      a[r] = fmaf(xv.w, fmaf(xv.w, iv4.w, m24.w), a[r]);
    }
  }
  // combine the two 64-d sub-halves within the wave
#pragma unroll
  for (int r = 0; r < 8; ++r) a[r] += __shfl_xor(a[r], 32, 64);

  if (h == 0) {
#pragma unroll
    for (int r = 0; r < 8; ++r) part[q][r][t] = a[r];
  }
  __syncthreads();

  // epilogue on first 4 waves: rr = row-in-block (0..7), t2 = component
  const int rr = tid >> 5, t2 = tid & 31;
  float kv = 0.f, lp = 0.f;
  if (tid < 256) {
    float quad = 0.f;
#pragma unroll
    for (int qq = 0; qq < 8; ++qq) quad += part[qq][rr][t2];
    // kl_gaussian = log_pdfs + entropy = D/2 - 0.5*quad (log_std_sum cancels)
    kv = 512.0f - 0.5f * (quad + c2[t2]);
    klg[(size_t)(row0 + rr) * NT + t2] = kv;

    // log_pi: exclusive prefix scan of log1p(-beta) within each 32-lane group
    const float b = beta[(size_t)(row0 + rr) * NT + t2];
    const float l1m = log1pf(-b);
    float s = l1m;
#pragma unroll
    for (int d = 1; d < 32; d <<= 1) {
      float v = __shfl_up(s, (unsigned)d, 32);
      if (t2 >= d) s += v;
    }
    lp = logf(b) + (s - l1m);   // exclusive prefix + log(beta)
    lpi[(size_t)(row0 + rr) * NT + t2] = lp;
  }
  __syncthreads();                 // all part reads done before reuse
  if (tid < 256) {
    part[0][rr][t2] = kv;
    part[1][rr][t2] = lp;
  }
  __syncthreads();
  if (tid < 32) {
    float sg = 0.f, sp = 0.f;
#pragma unroll
    for (int r = 0; r < 8; ++r) { sg += part[0][r][tid]; sp += part[1][r][tid]; }
    atomicAdd(&Ng[tid],  sg);
    atomicAdd(&Npi[tid], sp);
  }
}

// ---------------------------------------------------------------------------
// Kernel D: mix, softmax over T, final weighted mean.
// grid = 512, block = 256 (4 waves, 2 rows per wave: one per 32-lane half)
// ---------------------------------------------------------------------------
__global__ __launch_bounds__(256) void k_final(const float* __restrict__ ws,
                                               float* __restrict__ out) {
  const float* Ng  = ws + OFF_NG;
  const float* Npi = ws + OFF_NPI;
  const float* klg = ws + OFF_KLG;
  const float* lpi = ws + OFF_LPI;

  const int tid  = threadIdx.x;
  const int wave = tid >> 6, lane = tid & 63;
  const int h = lane >> 5, t = lane & 31;
  const int row = blockIdx.x * 8 + wave * 2 + h;

  const float kg = klg[(size_t)row * NT + t];
  const float lp = lpi[(size_t)row * NT + t];
  const float ng = Ng[t], np = Npi[t];
  const float mix  = np / (ng + np);
  const float klgm = mix * kg;
  const float kl   = klgm + (1.0f - mix) * lp;

  // softmax over the 32 t-lanes (masks < 32 stay within each half)
  float m = kl;
#pragma unroll
  for (int mk = 16; mk >= 1; mk >>= 1) m = fmaxf(m, __shfl_xor(m, mk, 64));
  const float e = expf(kl - m);
  float num = e * klgm, den = e;
#pragma unroll
  for (int mk = 16; mk >= 1; mk >>= 1) {
    num += __shfl_xor(num, mk, 64);
    den += __shfl_xor(den, mk, 64);
  }
  float s = num / den;           // per-row sum_t phi*klgm (replicated in group)
  s += __shfl_xor(s, 32, 64);    // 2 rows of this wave

  __shared__ float red[4];
  if (lane == 0) red[wave] = s;
  __syncthreads();
  if (tid == 0)
    atomicAdd(out, (red[0] + red[1] + red[2] + red[3]) * (1.0f / (float)NB));
}

// ---------------------------------------------------------------------------
extern "C" void kernel_launch(void* const* d_in, const int* in_sizes, int n_in,
                              void* d_out, int out_size, void* d_ws, size_t ws_size,
                              hipStream_t stream) {
  const float* x    = (const float*)d_in[0];
  const float* mu   = (const float*)d_in[1];
  const float* rho  = (const float*)d_in[2];
  const float* beta = (const float*)d_in[3];
  float* out = (float*)d_out;
  float* ws  = (float*)d_ws;

  hipLaunchKernelGGL(k_stats, dim3(32),  dim3(256), 0, stream, mu, rho, ws, out);
  hipLaunchKernelGGL(k_main,  dim3(512), dim3(512), 0, stream, x, beta, ws);
  hipLaunchKernelGGL(k_final, dim3(512), dim3(256), 0, stream, ws, out);
}